// Round 1
// 1705.452 us; speedup vs baseline: 1.7056x; 1.7056x over previous
//
#include <hip/hip_runtime.h>
#include <hip/hip_bf16.h>
#include <math.h>

#define HID 4096
#define DH  128
#define NQH 32
#define NKVH 8
#define BB  2
#define TQ  2048
#define BT  (BB*TQ)

typedef __bf16 bf16x8 __attribute__((ext_vector_type(8)));
typedef __bf16 bf16x4 __attribute__((ext_vector_type(4)));
typedef float  f32x4  __attribute__((ext_vector_type(4)));
typedef float  f32x16 __attribute__((ext_vector_type(16)));

#define MFMA(a,b,c)   __builtin_amdgcn_mfma_f32_16x16x32_bf16(a,b,c,0,0,0)
#define MFMA32(a,b,c) __builtin_amdgcn_mfma_f32_32x32x16_bf16(a,b,c,0,0,0)

// LDS tiles are [row][64] bf16 with a 16B-granule XOR swizzle so that both the
// staging writes and the MFMA fragment reads hit the LDS bank-cycle floor.
// A (rows = M, lanes read 32 consecutive rows at one k-granule): g ^= m&7.
// B (rows = N; writes arrive as n = 4*lane+j, reads as n consecutive):
//   g ^= (n ^ (n>>2)) & 7  -- spans all 8 granules on BOTH access patterns.
__device__ __forceinline__ int aIdx(int m, int k) {
    return (m << 6) + ((((k >> 3) ^ (m & 7)) << 3) | (k & 7));
}
__device__ __forceinline__ int bIdx(int n, int k) {
    return (n << 6) + ((((k >> 3) ^ ((n ^ (n >> 2)) & 7)) << 3) | (k & 7));
}

// ---------------------------------------------------------------------------
// x fp32 -> bf16, plain row-major copy (xb lives in the upper half of d_out,
// which is dead until ogemm overwrites it at the very end).
// ---------------------------------------------------------------------------
__global__ __launch_bounds__(256) void conv_kernel(
    const float* __restrict__ x, __bf16* __restrict__ xb)
{
    const size_t i = (((size_t)blockIdx.x << 8) + threadIdx.x) << 3;
    const f32x4 f0 = *(const f32x4*)(x + i);
    const f32x4 f1 = *(const f32x4*)(x + i + 4);
    bf16x8 o;
    #pragma unroll
    for (int j = 0; j < 4; ++j) { o[j] = (__bf16)f0[j]; o[j + 4] = (__bf16)f1[j]; }
    *(bf16x8*)(xb + i) = o;
}

// ---------------------------------------------------------------------------
// QKV GEMM: xb(bf16)[4096 x 4096] @ W(fp32->bf16)[4096 x 128-col head slice].
// 128x128 tile, BK=64, 8 waves (2x4), 32x32x16 MFMA, reg-prefetched staging.
// Epilogue: Q/K -> RMSnorm+RoPE; V -> transposed store, via LDS Ct (union).
// ---------------------------------------------------------------------------
__global__ __launch_bounds__(512,4) void qkv_kernel(
    const __bf16* __restrict__ xb, const float* __restrict__ wq,
    const float* __restrict__ wk,  const float* __restrict__ wv,
    const float* __restrict__ qnw, const float* __restrict__ knw,
    __bf16* __restrict__ qb, __bf16* __restrict__ kb, __bf16* __restrict__ vt)
{
    __shared__ union {
        struct { __bf16 A[128*64]; __bf16 B[128*64]; } s;
        float Ct[128][133];                 // 133: odd-ish stride, col reads conflict-free
    } u;

    // bijective XCD-chunked mapping: each XCD owns 6 consecutive col-tiles ->
    // its 2MB W panel stays L2-resident across all 32 row-tiles.
    const int bid = blockIdx.x;
    const int wg  = (bid & 7) * 192 + (bid >> 3);
    const int ct  = wg >> 5;                 // 0..47: 32 Q heads, 8 K, 8 V
    const int rt  = wg & 31;
    const int tid = threadIdx.x;
    const int lane = tid & 63;
    const int wave = tid >> 6;
    const int wr = wave >> 2, wc = wave & 3; // wave tile: 64 rows x 32 cols
    const int l31 = lane & 31, hi = lane >> 5;

    const float* W; int Ncols, kind, hsel;
    if (ct < NQH)            { W = wq; Ncols = NQH*DH;  hsel = ct;          kind = 0; }
    else if (ct < NQH+NKVH)  { W = wk; Ncols = NKVH*DH; hsel = ct-NQH;      kind = 1; }
    else                     { W = wv; Ncols = NKVH*DH; hsel = ct-NQH-NKVH; kind = 2; }
    const int col0 = hsel * DH;
    const int row0 = rt << 7;

    // A staging: thread -> (row am / am+64, granule ag); coalesced 16B loads.
    const int am = tid >> 3, ag = tid & 7;
    const int as0 = aIdx(am,      ag << 3);
    const int as1 = aIdx(am + 64, ag << 3);
    // B staging: thread loads 4 rows (k) x float4 (n), transposes in-reg.
    const int bn0 = (tid & 31) << 2;
    const int bk0 = (tid >> 5) << 2;
    int bso[4];
    #pragma unroll
    for (int j = 0; j < 4; ++j) bso[j] = bIdx(bn0 + j, bk0);

    // fragment read bases
    const int aoff0 = ((wr << 6) + l31) << 6;
    const int aoff1 = aoff0 + (32 << 6);
    const int axor  = l31 & 7;
    const int nB    = (wc << 5) + l31;
    const int boff  = nB << 6;
    const int bxor  = (nB ^ (nB >> 2)) & 7;

    const __bf16* apA = xb + (size_t)(row0 + am) * HID + (ag << 3);
    const float*  bpB = W + (size_t)bk0 * Ncols + col0 + bn0;

    f32x16 acc0 = {0.f,0.f,0.f,0.f,0.f,0.f,0.f,0.f,0.f,0.f,0.f,0.f,0.f,0.f,0.f,0.f};
    f32x16 acc1 = {0.f,0.f,0.f,0.f,0.f,0.f,0.f,0.f,0.f,0.f,0.f,0.f,0.f,0.f,0.f,0.f};

    // preload k0 = 0
    bf16x8 a0 = *(const bf16x8*)(apA);
    bf16x8 a1 = *(const bf16x8*)(apA + (size_t)64 * HID);
    f32x4 w0 = *(const f32x4*)(bpB);
    f32x4 w1 = *(const f32x4*)(bpB + Ncols);
    f32x4 w2 = *(const f32x4*)(bpB + 2 * Ncols);
    f32x4 w3 = *(const f32x4*)(bpB + 3 * Ncols);

    for (int k0 = 0; k0 < HID; k0 += 64) {
        __syncthreads();                       // prev iter's frag reads done
        *(bf16x8*)&u.s.A[as0] = a0;
        *(bf16x8*)&u.s.A[as1] = a1;
        #pragma unroll
        for (int j = 0; j < 4; ++j) {
            bf16x4 bv;
            bv[0] = (__bf16)w0[j]; bv[1] = (__bf16)w1[j];
            bv[2] = (__bf16)w2[j]; bv[3] = (__bf16)w3[j];
            *(bf16x4*)&u.s.B[bso[j]] = bv;
        }
        __syncthreads();                       // tiles visible
        if (k0 + 64 < HID) {                   // prefetch next tile into regs;
            const __bf16* an = apA + k0 + 64;  // VMEM latency hides under MFMA
            a0 = *(const bf16x8*)(an);
            a1 = *(const bf16x8*)(an + (size_t)64 * HID);
            const float* bn_ = bpB + (size_t)(k0 + 64) * Ncols;
            w0 = *(const f32x4*)(bn_);
            w1 = *(const f32x4*)(bn_ + Ncols);
            w2 = *(const f32x4*)(bn_ + 2 * Ncols);
            w3 = *(const f32x4*)(bn_ + 3 * Ncols);
        }
        #pragma unroll
        for (int kr = 0; kr < 4; ++kr) {
            const int kg = (kr << 1) + hi;
            bf16x8 fa0 = *(const bf16x8*)&u.s.A[aoff0 + ((kg ^ axor) << 3)];
            bf16x8 fa1 = *(const bf16x8*)&u.s.A[aoff1 + ((kg ^ axor) << 3)];
            bf16x8 fb  = *(const bf16x8*)&u.s.B[boff  + ((kg ^ bxor) << 3)];
            acc0 = MFMA32(fa0, fb, acc0);
            acc1 = MFMA32(fa1, fb, acc1);
        }
    }

    __syncthreads();                           // last frag reads done -> reuse LDS as Ct
    #pragma unroll
    for (int mr = 0; mr < 2; ++mr) {
        const f32x16 a = mr ? acc1 : acc0;
        #pragma unroll
        for (int r = 0; r < 16; ++r) {
            const int row = (wr << 6) + (mr << 5) + (r & 3) + ((r >> 2) << 3) + (hi << 2);
            u.Ct[row][(wc << 5) + l31] = a[r];
        }
    }
    __syncthreads();

    const int bidx = row0 >> 11;               // 128-row tile never crosses batch
    if (kind == 2) {
        // V: transposed store [b][hkv][d][t]
        const int d  = tid >> 2;
        const int t0 = (tid & 3) << 5;
        __bf16* dst = vt + ((size_t)(bidx*NKVH + hsel)*DH + d)*TQ + (row0 & (TQ-1)) + t0;
        #pragma unroll
        for (int c = 0; c < 8; ++c) {
            bf16x4 o;
            #pragma unroll
            for (int i = 0; i < 4; ++i) o[i] = (__bf16)u.Ct[t0 + (c << 2) + i][d];
            *(bf16x4*)(dst + (c << 2)) = o;
        }
    } else {
        // Q/K: RMS norm over 128 then RoPE
        const int r  = tid >> 2;
        const int c0 = (tid & 3) << 5;
        float ss = 0.f;
        #pragma unroll
        for (int i = 0; i < 32; ++i) { const float v = u.Ct[r][c0 + i]; ss += v * v; }
        ss += __shfl_xor(ss, 1); ss += __shfl_xor(ss, 2);
        const float inv = rsqrtf(ss * (1.0f/DH) + 1e-6f);
        const float* nw = kind ? knw : qnw;
        const int tpos = (row0 & (TQ-1)) + r;
        __bf16* dst = (kind == 0)
            ? qb + ((size_t)(bidx*NQH  + hsel)*TQ + tpos)*DH + c0
            : kb + ((size_t)(bidx*NKVH + hsel)*TQ + tpos)*DH + c0;
        #pragma unroll
        for (int cc = 0; cc < 8; ++cc) {
            bf16x4 o;
            #pragma unroll
            for (int i = 0; i < 4; ++i) {
                const int c = c0 + (cc << 2) + i;
                const float nv = nw[c]      * u.Ct[r][c]      * inv;
                const float pv = nw[c ^ 64] * u.Ct[r][c ^ 64] * inv;
                // timescale = THETA^(i/64); angle = t / timescale
                const float ang = (float)tpos * exp2f(-0.31143075895f * (float)(c & 63));
                float sn, cs; sincosf(ang, &sn, &cs);
                o[i] = (__bf16)((c < 64) ? (nv*cs - pv*sn) : (nv*cs + pv*sn));
            }
            *(bf16x4*)(dst + (cc << 2)) = o;
        }
    }
}

// ---------------------------------------------------------------------------
// Flash attention, causal, GQA. 1 wave per (b, h, 16-row Q tile). (unchanged)
// ---------------------------------------------------------------------------
__global__ __launch_bounds__(64) void attn_kernel(
    const __bf16* __restrict__ qb, const __bf16* __restrict__ kb,
    const __bf16* __restrict__ vt, __bf16* __restrict__ ab)
{
    const int qt = blockIdx.x;
    const int bh = blockIdx.y;
    const int b = bh >> 5, h = bh & 31, hk = h >> 2;
    const int lane = threadIdx.x;
    const int m16 = lane & 15, quad = lane >> 4;

    const __bf16* qp = qb + (size_t)(b*NQH  + h )*TQ*DH;
    const __bf16* kp = kb + (size_t)(b*NKVH + hk)*TQ*DH;
    const __bf16* vp = vt + (size_t)(b*NKVH + hk)*DH*TQ;   // [d][t]

    const int q0 = qt << 4;
    bf16x8 aq[4];
    #pragma unroll
    for (int ks = 0; ks < 4; ++ks)
        aq[ks] = *(const bf16x8*)(qp + (size_t)(q0 + m16)*DH + (ks << 5) + (quad << 3));

    f32x4 o[8];
    #pragma unroll
    for (int cc = 0; cc < 8; ++cc) o[cc] = (f32x4){0.f,0.f,0.f,0.f};
    float mrow[4] = {-1e30f,-1e30f,-1e30f,-1e30f};
    float lrow[4] = {0.f,0.f,0.f,0.f};

    __shared__ alignas(16) __bf16 Pl[16][40];
    const float scale = 0.08838834764831845f;   // 1/sqrt(128)

    const int ktmax = (q0 + 15) >> 5;
    for (int kt = 0; kt <= ktmax; ++kt) {
        const int k0 = kt << 5;
        f32x4 s0 = {0.f,0.f,0.f,0.f}, s1 = {0.f,0.f,0.f,0.f};
        #pragma unroll
        for (int ks = 0; ks < 4; ++ks) {
            bf16x8 b0 = *(const bf16x8*)(kp + (size_t)(k0 + m16)*DH      + (ks << 5) + (quad << 3));
            bf16x8 b1 = *(const bf16x8*)(kp + (size_t)(k0 + 16 + m16)*DH + (ks << 5) + (quad << 3));
            s0 = MFMA(aq[ks], b0, s0);
            s1 = MFMA(aq[ks], b1, s1);
        }
        float alpha[4];
        #pragma unroll
        for (int r = 0; r < 4; ++r) {
            const int qg = q0 + (quad << 2) + r;
            const int kg = k0 + m16;
            float a_ = (kg      <= qg) ? s0[r]*scale : -1e30f;
            float b_ = (kg + 16 <= qg) ? s1[r]*scale : -1e30f;
            float t = fmaxf(a_, b_);
            t = fmaxf(t, __shfl_xor(t, 1)); t = fmaxf(t, __shfl_xor(t, 2));
            t = fmaxf(t, __shfl_xor(t, 4)); t = fmaxf(t, __shfl_xor(t, 8));
            const float mn = fmaxf(mrow[r], t);
            alpha[r] = __expf(mrow[r] - mn);
            const float p0 = __expf(a_ - mn);
            const float p1 = __expf(b_ - mn);
            float rs = p0 + p1;
            rs += __shfl_xor(rs, 1); rs += __shfl_xor(rs, 2);
            rs += __shfl_xor(rs, 4); rs += __shfl_xor(rs, 8);
            lrow[r] = lrow[r]*alpha[r] + rs;
            mrow[r] = mn;
            Pl[(quad << 2) + r][m16]      = (__bf16)p0;
            Pl[(quad << 2) + r][m16 + 16] = (__bf16)p1;
        }
        __syncthreads();
        const bf16x8 pf = *(const bf16x8*)&Pl[m16][quad << 3];
        #pragma unroll
        for (int cc = 0; cc < 8; ++cc) {
            #pragma unroll
            for (int r = 0; r < 4; ++r) o[cc][r] *= alpha[r];
            bf16x8 vf = *(const bf16x8*)(vp + (size_t)((cc << 4) + m16)*TQ + k0 + (quad << 3));
            o[cc] = MFMA(pf, vf, o[cc]);
        }
        __syncthreads();
    }

    #pragma unroll
    for (int r = 0; r < 4; ++r) {
        const int t = q0 + (quad << 2) + r;
        const float invl = 1.0f / lrow[r];
        __bf16* dst = ab + (size_t)(b*TQ + t)*(NQH*DH) + h*DH + m16;
        #pragma unroll
        for (int cc = 0; cc < 8; ++cc)
            dst[cc << 4] = (__bf16)(o[cc][r] * invl);
    }
}

// ---------------------------------------------------------------------------
// Output GEMM: ab(bf16)[BT x 4096] @ wo(fp32->bf16)[4096 x 4096] -> out fp32.
// Same 128x128 structure as qkv; direct fp32 stores from the accumulator.
// ---------------------------------------------------------------------------
__global__ __launch_bounds__(512,4) void ogemm_kernel(
    const __bf16* __restrict__ Am, const float* __restrict__ W,
    float* __restrict__ out)
{
    __shared__ struct { __bf16 A[128*64]; __bf16 B[128*64]; } s;

    const int bid = blockIdx.x;
    const int wg  = (bid & 7) * 128 + (bid >> 3);
    const int ct  = wg >> 5, rt = wg & 31;
    const int tid = threadIdx.x;
    const int lane = tid & 63;
    const int wave = tid >> 6;
    const int wr = wave >> 2, wc = wave & 3;
    const int l31 = lane & 31, hi = lane >> 5;
    const int col0 = ct << 7;
    const int row0 = rt << 7;

    const int am = tid >> 3, ag = tid & 7;
    const int as0 = aIdx(am,      ag << 3);
    const int as1 = aIdx(am + 64, ag << 3);
    const int bn0 = (tid & 31) << 2;
    const int bk0 = (tid >> 5) << 2;
    int bso[4];
    #pragma unroll
    for (int j = 0; j < 4; ++j) bso[j] = bIdx(bn0 + j, bk0);

    const int aoff0 = ((wr << 6) + l31) << 6;
    const int aoff1 = aoff0 + (32 << 6);
    const int axor  = l31 & 7;
    const int nB    = (wc << 5) + l31;
    const int boff  = nB << 6;
    const int bxor  = (nB ^ (nB >> 2)) & 7;

    const __bf16* apA = Am + (size_t)(row0 + am) * HID + (ag << 3);
    const float*  bpB = W + (size_t)bk0 * HID + col0 + bn0;

    f32x16 acc0 = {0.f,0.f,0.f,0.f,0.f,0.f,0.f,0.f,0.f,0.f,0.f,0.f,0.f,0.f,0.f,0.f};
    f32x16 acc1 = {0.f,0.f,0.f,0.f,0.f,0.f,0.f,0.f,0.f,0.f,0.f,0.f,0.f,0.f,0.f,0.f};

    bf16x8 a0 = *(const bf16x8*)(apA);
    bf16x8 a1 = *(const bf16x8*)(apA + (size_t)64 * HID);
    f32x4 w0 = *(const f32x4*)(bpB);
    f32x4 w1 = *(const f32x4*)(bpB + HID);
    f32x4 w2 = *(const f32x4*)(bpB + 2 * HID);
    f32x4 w3 = *(const f32x4*)(bpB + 3 * HID);

    for (int k0 = 0; k0 < HID; k0 += 64) {
        __syncthreads();
        *(bf16x8*)&s.A[as0] = a0;
        *(bf16x8*)&s.A[as1] = a1;
        #pragma unroll
        for (int j = 0; j < 4; ++j) {
            bf16x4 bv;
            bv[0] = (__bf16)w0[j]; bv[1] = (__bf16)w1[j];
            bv[2] = (__bf16)w2[j]; bv[3] = (__bf16)w3[j];
            *(bf16x4*)&s.B[bso[j]] = bv;
        }
        __syncthreads();
        if (k0 + 64 < HID) {
            const __bf16* an = apA + k0 + 64;
            a0 = *(const bf16x8*)(an);
            a1 = *(const bf16x8*)(an + (size_t)64 * HID);
            const float* bn_ = bpB + (size_t)(k0 + 64) * HID;
            w0 = *(const f32x4*)(bn_);
            w1 = *(const f32x4*)(bn_ + HID);
            w2 = *(const f32x4*)(bn_ + 2 * HID);
            w3 = *(const f32x4*)(bn_ + 3 * HID);
        }
        #pragma unroll
        for (int kr = 0; kr < 4; ++kr) {
            const int kg = (kr << 1) + hi;
            bf16x8 fa0 = *(const bf16x8*)&s.A[aoff0 + ((kg ^ axor) << 3)];
            bf16x8 fa1 = *(const bf16x8*)&s.A[aoff1 + ((kg ^ axor) << 3)];
            bf16x8 fb  = *(const bf16x8*)&s.B[boff  + ((kg ^ bxor) << 3)];
            acc0 = MFMA32(fa0, fb, acc0);
            acc1 = MFMA32(fa1, fb, acc1);
        }
    }

    #pragma unroll
    for (int mr = 0; mr < 2; ++mr) {
        const f32x16 a = mr ? acc1 : acc0;
        #pragma unroll
        for (int r = 0; r < 16; ++r) {
            const int row = row0 + (wr << 6) + (mr << 5) + (r & 3) + ((r >> 2) << 3) + (hi << 2);
            out[(size_t)row * HID + col0 + (wc << 5) + l31] = a[r];
        }
    }
}

extern "C" void kernel_launch(void* const* d_in, const int* in_sizes, int n_in,
                              void* d_out, int out_size, void* d_ws, size_t ws_size,
                              hipStream_t stream)
{
    const float* x   = (const float*)d_in[0];
    const float* wq  = (const float*)d_in[1];
    const float* wk  = (const float*)d_in[2];
    const float* wv  = (const float*)d_in[3];
    const float* wo  = (const float*)d_in[4];
    const float* qnw = (const float*)d_in[5];
    const float* knw = (const float*)d_in[6];
    float* out = (float*)d_out;

    // d_out (67 MB fp32) double-duty:
    //   lower half: qb (bf16) - read by attn strictly before ogemm writes out.
    //   upper half: xb (bf16) - read by qkv, dead before attn/ogemm run.
    __bf16* qb = (__bf16*)d_out;                        // [B][32][T][128]  33.5 MB
    __bf16* xb = (__bf16*)d_out + (size_t)BB*NQH*TQ*DH; // [BT][4096]      33.5 MB
    __bf16* kb = (__bf16*)d_ws;                         // [B][8][T][128]    8.4 MB
    __bf16* vt = kb + (size_t)BB*NKVH*TQ*DH;            // [B][8][128][T]    8.4 MB
    __bf16* ab = vt + (size_t)BB*NKVH*TQ*DH;            // [B][T][4096]     33.5 MB
    const size_t need = ((size_t)BB*NKVH*TQ*DH*2 + (size_t)BB*TQ*NQH*DH)*sizeof(__bf16);
    if (ws_size < need) return;   // deterministic no-op -> diagnosable absmax

    conv_kernel<<<dim3((BT*HID)/2048), 256, 0, stream>>>(x, xb);
    qkv_kernel<<<dim3(48*32), 512, 0, stream>>>(xb, wq, wk, wv, qnw, knw, qb, kb, vt);
    attn_kernel<<<dim3(TQ/16, BB*NQH), 64, 0, stream>>>(qb, kb, vt, ab);
    ogemm_kernel<<<dim3(32*32), 512, 0, stream>>>(ab, wo, out);
}